// Round 4
// baseline (1022.594 us; speedup 1.0000x reference)
//
#include <hip/hip_runtime.h>
#include <hip/hip_bf16.h>

typedef _Float16 f16;
typedef _Float16 f16x8 __attribute__((ext_vector_type(8)));

#define D 128
#define N_CLS 40

// Gather operand (GEMM output) is feature-sliced: 8 slices x 16 feats (32B/row),
// slice-major: HS_blk[s][i][f], elem offset = s*(n*16) + i*16 + f.
// Slice s is processed only by blocks with blockIdx.x%8==s -> XCD s (round-robin
// dispatch) -> per-XCD gather working set = n*32B = 3.2MB < 4MB L2. [confirmed
// round 2: agg FETCH_SIZE 363MB -> 74MB]
// Aggregation OUTPUT is row-major (consumed densely by GEMM2 / classifier).

// ---- preprocessing v2: deg count -> scan -> direct placement ----

__global__ __launch_bounds__(256) void k_deg(const int* __restrict__ dst,
                                             int* __restrict__ deg, int e) {
  int stride = gridDim.x * blockDim.x;
  for (int q = blockIdx.x * blockDim.x + threadIdx.x; q < e; q += stride)
    atomicAdd(&deg[dst[q]], 1);
}

__global__ __launch_bounds__(1024) void k_bsum(const int* __restrict__ deg,
                                               int* __restrict__ bsum, int n) {
  __shared__ int s[1024];
  int t = threadIdx.x;
  int i = blockIdx.x * 1024 + t;
  s[t] = (i < n) ? deg[i] : 0;
  __syncthreads();
  for (int off = 512; off > 0; off >>= 1) {
    if (t < off) s[t] += s[t + off];
    __syncthreads();
  }
  if (t == 0) bsum[blockIdx.x] = s[0];
}

__global__ __launch_bounds__(128) void k_sscan(int* __restrict__ bsum, int nblk) {
  __shared__ int s[128];
  int t = threadIdx.x;
  int v = (t < nblk) ? bsum[t] : 0;
  s[t] = v;
  __syncthreads();
  for (int off = 1; off < 128; off <<= 1) {
    int a = (t >= off) ? s[t - off] : 0;
    __syncthreads();
    s[t] += a;
    __syncthreads();
  }
  if (t < nblk) bsum[t] = s[t] - v;  // exclusive
}

__global__ __launch_bounds__(1024) void k_rowfin(const int* __restrict__ deg,
                                                 const int* __restrict__ bsum,
                                                 int* __restrict__ row_start,
                                                 int* __restrict__ cur,
                                                 float* __restrict__ isd, int n) {
  __shared__ int s[1024];
  int t = threadIdx.x;
  int i = blockIdx.x * 1024 + t;
  int v = (i < n) ? deg[i] : 0;
  s[t] = v;
  __syncthreads();
  for (int off = 1; off < 1024; off <<= 1) {
    int a = (t >= off) ? s[t - off] : 0;
    __syncthreads();
    s[t] += a;
    __syncthreads();
  }
  if (i < n) {
    int excl = bsum[blockIdx.x] + s[t] - v;
    row_start[i] = excl;
    cur[i] = excl;
    isd[i] = rsqrtf((float)(v + 1));
  }
}

__global__ __launch_bounds__(256) void k_place2(const int* __restrict__ src,
                                                const int* __restrict__ dst,
                                                int* __restrict__ cur,
                                                int* __restrict__ csr, int e) {
  int stride = gridDim.x * blockDim.x;
  for (int q = blockIdx.x * blockDim.x + threadIdx.x; q < e; q += stride) {
    int p = atomicAdd(&cur[dst[q]], 1);
    csr[p] = src[q];
  }
}

// ---- tiled GEMM: HS_blk = isd[i] * (X @ W), fp32 accum, f16 slice-major out ----
// HALF_IN input is ROW-MAJOR f16 [n][128] (agg output); fp32 input row-major.
template <bool HALF_IN>
__global__ __launch_bounds__(256) void k_gemm_t(const void* __restrict__ Xv,
                                                const float* __restrict__ W,
                                                const float* __restrict__ isd,
                                                f16* __restrict__ HS, int n) {
  __shared__ float Xt[64][D + 4];
  __shared__ float Wb[32][D + 4];
  const size_t ss = (size_t)n * 16;  // slice stride in f16 elems
  int t = threadIdx.x;
  int r0 = blockIdx.x * 64;
  if (!HALF_IN) {
    const float* X = (const float*)Xv;
    for (int q = t; q < 64 * 32; q += 256) {
      int row = q >> 5, cb = (q & 31) << 2;
      float4 v = {0.f, 0.f, 0.f, 0.f};
      if (r0 + row < n) v = *(const float4*)(X + (size_t)(r0 + row) * D + cb);
      *(float4*)&Xt[row][cb] = v;
    }
  } else {
    const f16* X = (const f16*)Xv;
    for (int q = t; q < 64 * 16; q += 256) {
      int row = q >> 4, cb = (q & 15) << 3;
      f16x8 v = 0;
      if (r0 + row < n) v = *(const f16x8*)(X + (size_t)(r0 + row) * D + cb);
      float* xp = &Xt[row][cb];
#pragma unroll
      for (int j = 0; j < 8; ++j) xp[j] = (float)v[j];
    }
  }
  int tr = ((t >> 4) & 15) << 2;
  int tc = (t & 15) << 3;
  float acc[4][8];
#pragma unroll
  for (int i = 0; i < 4; ++i)
#pragma unroll
    for (int j = 0; j < 8; ++j) acc[i][j] = 0.f;

  for (int hh = 0; hh < 4; ++hh) {
    __syncthreads();
    for (int q = t; q < 32 * 32; q += 256) {
      int row = q >> 5, cb = (q & 31) << 2;
      *(float4*)&Wb[row][cb] = *(const float4*)(W + (size_t)(hh * 32 + row) * D + cb);
    }
    __syncthreads();
#pragma unroll 4
    for (int k = 0; k < 32; ++k) {
      float4 u0 = *(const float4*)&Wb[k][tc];
      float4 u1 = *(const float4*)&Wb[k][tc + 4];
      float bv[8] = {u0.x, u0.y, u0.z, u0.w, u1.x, u1.y, u1.z, u1.w};
      int kk = hh * 32 + k;
#pragma unroll
      for (int i = 0; i < 4; ++i) {
        float a = Xt[tr + i][kk];
#pragma unroll
        for (int j = 0; j < 8; ++j) acc[i][j] += a * bv[j];
      }
    }
  }
#pragma unroll
  for (int i = 0; i < 4; ++i) {
    int row = r0 + tr + i;
    if (row < n) {
      float s = isd[row];
      f16x8 ov;
#pragma unroll
      for (int j = 0; j < 8; ++j) ov[j] = (f16)(s * acc[i][j]);
      // slice-major store (gather operand)
      *(f16x8*)(HS + (size_t)(tc >> 4) * ss + (size_t)row * 16 + (tc & 15)) = ov;
    }
  }
}

__device__ inline f16x8 shfl_xor_f16x8(f16x8 v, int m) {
  union { f16x8 h; int i[4]; } u;
  u.h = v;
#pragma unroll
  for (int k = 0; k < 4; ++k) u.i[k] = __shfl_xor(u.i[k], m);
  return u.h;
}

// ---- sliced aggregation: G[i][s*16..] = relu(isd[i]*(sum HS_blk[s][src] + self)+b)
// block: 256 thr = 4 waves; wave: 4 nodes (16-lane groups); group: 8 edge slots
// x 2 half-rows. 32 edges in flight per iteration (4 HS + 4 csr loads/lane).
// slice s = blockIdx.x & 7 (-> XCD s). Output G is ROW-MAJOR [n][128].
__global__ __launch_bounds__(256) void k_aggs(const f16* __restrict__ HS,
                                              const int* __restrict__ csr,
                                              const int* __restrict__ row_start,
                                              const int* __restrict__ deg,
                                              const float* __restrict__ isd,
                                              const float* __restrict__ bias,
                                              f16* __restrict__ G, int n) {
  const size_t ss = (size_t)n * 16;
  int t = threadIdx.x;
  int wave = t >> 6, lane = t & 63;
  int g = lane >> 4, r = lane & 15;
  int s = blockIdx.x & 7;
  int i0 = ((blockIdx.x >> 3) << 4) + (wave << 2) + g;
  bool ok = i0 < n;
  int i = ok ? i0 : n - 1;
  int hf = r & 1, er = r >> 1;
  int dg = deg[i];
  const int* cp = csr + row_start[i];
  const f16* sb = HS + (size_t)s * ss + (size_t)(hf << 3);
  f16x8 a0 = (f16x8)0, a1 = (f16x8)0, a2 = (f16x8)0, a3 = (f16x8)0;
  if (dg > 0) {
    int dgm = dg - 1;
    // csr prefetch pipeline: indices for the NEXT 32-edge window are issued
    // before the current HS loads, keeping 8 loads/lane in flight.
    int iA = cp[min(er, dgm)];
    int iB = cp[min(er + 8, dgm)];
    int iC = cp[min(er + 16, dgm)];
    int iD = cp[min(er + 24, dgm)];
    for (int u = 0; u < dg; u += 32) {
      int cA = iA, cB = iB, cC = iC, cD = iD;
      iA = cp[min(u + 32 + er, dgm)];
      iB = cp[min(u + 40 + er, dgm)];
      iC = cp[min(u + 48 + er, dgm)];
      iD = cp[min(u + 56 + er, dgm)];
      if (u + er < dg)
        a0 += *(const f16x8*)(sb + ((size_t)(unsigned)cA << 4));
      if (u + 8 + er < dg)
        a1 += *(const f16x8*)(sb + ((size_t)(unsigned)cB << 4));
      if (u + 16 + er < dg)
        a2 += *(const f16x8*)(sb + ((size_t)(unsigned)cC << 4));
      if (u + 24 + er < dg)
        a3 += *(const f16x8*)(sb + ((size_t)(unsigned)cD << 4));
    }
  }
  // reduce 8 edge-slots within the 16-lane group (3 levels, stays in-group)
  f16x8 tv = (a0 + a1) + (a2 + a3);
  tv += shfl_xor_f16x8(tv, 2);
  tv += shfl_xor_f16x8(tv, 4);
  tv += shfl_xor_f16x8(tv, 8);
  // epilogue: self-loop + isd + bias + relu
  f16x8 sv = *(const f16x8*)(HS + (size_t)s * ss + (size_t)i * 16 + (hf << 3));
  float di = isd[i];
  const float* bp = bias + s * 16 + (hf << 3);
  float4 b0 = *(const float4*)bp;
  float4 b1 = *(const float4*)(bp + 4);
  float bv[8] = {b0.x, b0.y, b0.z, b0.w, b1.x, b1.y, b1.z, b1.w};
  f16x8 ov;
#pragma unroll
  for (int j = 0; j < 8; ++j) {
    float v = di * ((float)tv[j] + (float)sv[j]) + bv[j];
    v = v > 0.f ? v : 0.f;
    ov[j] = (f16)v;
  }
  if (ok && r < 2)
    *(f16x8*)(G + (size_t)i * D + s * 16 + (hf << 3)) = ov;
}

// ---- classifier v3: out = H @ Wl + bl, Wl^T staged in LDS, 128 nodes/block ----
// 4 waves x 4 nodes per pass, 8 passes. Per 16-lane group: one node; lane l
// holds h[l*8..l*8+7] in regs; per class: 2 x b128 LDS (Wlt row, aligned) +
// 8 FMA + 4-shuffle butterfly; class c kept by lane c&15 in slot c>>4.
__global__ __launch_bounds__(256) void k_cls(const f16* __restrict__ H,
                                             const float* __restrict__ Wl,
                                             const float* __restrict__ bl,
                                             float* __restrict__ out, int n) {
  __shared__ float wt[N_CLS][D];  // wt[c][k] = Wl[k][c]; rows 512B -> b128 ok
  int t = threadIdx.x;
  for (int q = t; q < D * N_CLS; q += 256) {
    int k = q / N_CLS, c = q - k * N_CLS;  // consecutive q = consecutive Wl
    wt[c][k] = Wl[q];
  }
  int wv = t >> 6, lane = t & 63, g = lane >> 4, l = lane & 15;
  float bb0 = bl[l];
  float bb1 = bl[16 + l];
  float bb2 = (l < 8) ? bl[32 + l] : 0.f;
  __syncthreads();
  int node0 = (blockIdx.x << 7) + (wv << 2) + g;
  for (int it = 0; it < 8; ++it) {
    int node = node0 + it * 16;
    if (node >= n) break;  // no barriers below: divergence safe
    f16x8 h = *(const f16x8*)(H + (size_t)node * D + l * 8);
    float hf[8];
#pragma unroll
    for (int j = 0; j < 8; ++j) hf[j] = (float)h[j];
    float r0 = bb0, r1 = bb1, r2 = bb2;
#pragma unroll 4
    for (int c = 0; c < N_CLS; ++c) {
      const float* wp = &wt[c][l * 8];
      float4 w0 = *(const float4*)wp;
      float4 w1 = *(const float4*)(wp + 4);
      float p = hf[0] * w0.x + hf[1] * w0.y + hf[2] * w0.z + hf[3] * w0.w +
                hf[4] * w1.x + hf[5] * w1.y + hf[6] * w1.z + hf[7] * w1.w;
      p += __shfl_xor(p, 1);
      p += __shfl_xor(p, 2);
      p += __shfl_xor(p, 4);
      p += __shfl_xor(p, 8);
      if ((c & 15) == l) {
        if (c < 16) r0 += p;
        else if (c < 32) r1 += p;
        else r2 += p;
      }
    }
    float* op = out + (size_t)node * N_CLS;
    op[l] = r0;
    op[16 + l] = r1;
    if (l < 8) op[32 + l] = r2;
  }
}

extern "C" void kernel_launch(void* const* d_in, const int* in_sizes, int n_in,
                              void* d_out, int out_size, void* d_ws, size_t ws_size,
                              hipStream_t stream) {
  const float* x  = (const float*)d_in[0];
  const int*   ei = (const int*)d_in[1];
  const float* W1 = (const float*)d_in[2];
  const float* b1 = (const float*)d_in[3];
  const float* W2 = (const float*)d_in[4];
  const float* b2 = (const float*)d_in[5];
  const float* Wl = (const float*)d_in[6];
  const float* bl = (const float*)d_in[7];
  float* out = (float*)d_out;

  const int n = in_sizes[0] / D;  // 100000
  const int e = in_sizes[1] / 2;  // 3200000
  const int* src = ei;
  const int* dst = ei + e;

  char* ws = (char*)d_ws;
  size_t off = 0;
  auto alloc = [&](size_t bytes) -> void* {
    void* p = ws + off;
    off += (bytes + 255) & ~(size_t)255;
    return p;
  };
  int*   deg       = (int*)alloc((size_t)n * 4);
  int*   row_start = (int*)alloc((size_t)n * 4);
  int*   cur       = (int*)alloc((size_t)n * 4);
  float* isd       = (float*)alloc((size_t)n * 4);
  int*   bsum      = (int*)alloc(128 * 4);
  int*   csr       = (int*)alloc((size_t)e * 4);
  f16*   hA        = (f16*)alloc((size_t)n * D * 2);
  f16*   hB        = (f16*)alloc((size_t)n * D * 2);

  hipMemsetAsync(deg, 0, (size_t)n * 4, stream);

  const int nblk = (n + 1023) / 1024;  // 98
  k_deg<<<1024, 256, 0, stream>>>(dst, deg, e);
  k_bsum<<<nblk, 1024, 0, stream>>>(deg, bsum, n);
  k_sscan<<<1, 128, 0, stream>>>(bsum, nblk);
  k_rowfin<<<nblk, 1024, 0, stream>>>(deg, bsum, row_start, cur, isd, n);
  k_place2<<<1024, 256, 0, stream>>>(src, dst, cur, csr, e);

  int gblocks = (n + 63) / 64;
  int ablocks = ((n + 15) / 16) * 8;  // node-groups x 8 slices (grid % 8 == 0)
  // layer 1: gemm -> slice-major hA; agg -> row-major hB
  k_gemm_t<false><<<gblocks, 256, 0, stream>>>(x, W1, isd, hA, n);
  k_aggs<<<ablocks, 256, 0, stream>>>(hA, csr, row_start, deg, isd, b1, hB, n);
  // layer 2: gemm (row-major in) -> slice-major hA; agg -> row-major hB
  k_gemm_t<true><<<gblocks, 256, 0, stream>>>(hB, W2, isd, hA, n);
  k_aggs<<<ablocks, 256, 0, stream>>>(hA, csr, row_start, deg, isd, b2, hB, n);
  // classifier
  k_cls<<<(n + 127) / 128, 256, 0, stream>>>(hB, Wl, bl, out, n);
}

// Round 5
// 693.948 us; speedup vs baseline: 1.4736x; 1.4736x over previous
//
#include <hip/hip_runtime.h>
#include <hip/hip_bf16.h>

typedef _Float16 f16;
typedef _Float16 f16x8 __attribute__((ext_vector_type(8)));

#define D 128
#define N_CLS 40
#define BN 128       // nodes per bucket
#define NBMAX 1024   // padded bucket count

// Gather operand (GEMM output) is feature-sliced: 8 slices x 16 feats (32B/row),
// slice-major: HS_blk[s][i][f], elem offset = s*(n*16) + i*16 + f.
// Slice s is processed only by blocks with blockIdx.x%8==s -> XCD s (round-robin
// dispatch) -> per-XCD gather working set = n*32B = 3.2MB < 4MB L2. [confirmed
// round 2: agg FETCH_SIZE 363MB -> 74MB]
// Aggregation OUTPUT is row-major (consumed densely by GEMM2 / classifier).
// Preprocessing: bucket-major two-stage scatter — confines random writes to
// 16KB windows (L1-resident). [round 4 showed the one-pass alternative costs
// 194MB of write-allocate traffic and 321us]

// ---- 1. bucket histogram of dst (LDS-staged) ----
__global__ __launch_bounds__(256) void k_hist(const int* __restrict__ dst,
                                              int* __restrict__ bcnt, int e) {
  __shared__ int lh[NBMAX];
  for (int j = threadIdx.x; j < NBMAX; j += 256) lh[j] = 0;
  __syncthreads();
  int stride = gridDim.x * blockDim.x;
  for (int q = blockIdx.x * blockDim.x + threadIdx.x; q < e; q += stride)
    atomicAdd(&lh[dst[q] >> 7], 1);
  __syncthreads();
  for (int j = threadIdx.x; j < NBMAX; j += 256)
    if (lh[j]) atomicAdd(&bcnt[j], lh[j]);
}

// ---- 2. exclusive scan of bucket counts ----
__global__ __launch_bounds__(1024) void k_bscan(const int* __restrict__ bcnt,
                                                int* __restrict__ bbase,
                                                int* __restrict__ bcur) {
  __shared__ int sums[NBMAX];
  int t = threadIdx.x;
  int c = bcnt[t];
  sums[t] = c;
  __syncthreads();
  for (int off = 1; off < NBMAX; off <<= 1) {
    int a = (t >= off) ? sums[t - off] : 0;
    __syncthreads();
    sums[t] += a;
    __syncthreads();
  }
  bbase[t] = sums[t] - c;
  bcur[t] = sums[t] - c;
}

// ---- 3. bin edges into bucket-major order ----
__global__ __launch_bounds__(256) void k_place(const int* __restrict__ src,
                                               const int* __restrict__ dst,
                                               int* __restrict__ bcur,
                                               unsigned int* __restrict__ binned,
                                               int e, int nwg) {
  __shared__ int lh[NBMAX];
  __shared__ int lofs[NBMAX];
  __shared__ int lcur[NBMAX];
  int chunk = (e + nwg - 1) / nwg;
  int lo = blockIdx.x * chunk;
  int hi = min(e, lo + chunk);
  int t = threadIdx.x;
  for (int j = t; j < NBMAX; j += 256) { lh[j] = 0; lcur[j] = 0; }
  __syncthreads();
  for (int q = lo + t; q < hi; q += 256) atomicAdd(&lh[dst[q] >> 7], 1);
  __syncthreads();
  for (int j = t; j < NBMAX; j += 256) {
    int c = lh[j];
    lofs[j] = c ? atomicAdd(&bcur[j], c) : 0;
  }
  __syncthreads();
  for (int q = lo + t; q < hi; q += 256) {
    int d = dst[q];
    int b = d >> 7;
    int r = atomicAdd(&lcur[b], 1);
    binned[lofs[b] + r] = ((unsigned int)(d & 127) << 17) | (unsigned int)src[q];
  }
}

// ---- 4. per-bucket counting sort -> CSR + deg + isd + row_start ----
__global__ __launch_bounds__(256) void k_csr(const unsigned int* __restrict__ binned,
                                             const int* __restrict__ bbase,
                                             int* __restrict__ csr,
                                             int* __restrict__ deg,
                                             float* __restrict__ isd,
                                             int* __restrict__ row_start, int n) {
  int b = blockIdx.x;
  int lo = bbase[b], hi = bbase[b + 1];
  __shared__ int h[BN];
  __shared__ int sc[BN];
  __shared__ int cur[BN];
  int t = threadIdx.x;
  if (t < BN) h[t] = 0;
  __syncthreads();
  for (int q = lo + t; q < hi; q += 256) atomicAdd(&h[binned[q] >> 17], 1);
  __syncthreads();
  if (t < BN) sc[t] = h[t];
  __syncthreads();
  for (int off = 1; off < BN; off <<= 1) {
    int a = 0;
    if (t < BN && t >= off) a = sc[t - off];
    __syncthreads();
    if (t < BN) sc[t] += a;
    __syncthreads();
  }
  if (t < BN) {
    int excl = sc[t] - h[t];
    cur[t] = lo + excl;
    int i = b * BN + t;
    if (i < n) {
      deg[i] = h[t];
      isd[i] = rsqrtf((float)(h[t] + 1));
      row_start[i] = lo + excl;
    }
  }
  __syncthreads();
  for (int q = lo + t; q < hi; q += 256) {
    unsigned int u = binned[q];
    int p = atomicAdd(&cur[u >> 17], 1);
    csr[p] = (int)(u & 0x1FFFF);
  }
}

// ---- tiled GEMM: HS_blk = isd[i] * (X @ W), fp32 accum, f16 slice-major out ----
// HALF_IN input is ROW-MAJOR f16 [n][128] (agg output); fp32 input row-major.
template <bool HALF_IN>
__global__ __launch_bounds__(256) void k_gemm_t(const void* __restrict__ Xv,
                                                const float* __restrict__ W,
                                                const float* __restrict__ isd,
                                                f16* __restrict__ HS, int n) {
  __shared__ float Xt[64][D + 4];
  __shared__ float Wb[32][D + 4];
  const size_t ss = (size_t)n * 16;  // slice stride in f16 elems
  int t = threadIdx.x;
  int r0 = blockIdx.x * 64;
  if (!HALF_IN) {
    const float* X = (const float*)Xv;
    for (int q = t; q < 64 * 32; q += 256) {
      int row = q >> 5, cb = (q & 31) << 2;
      float4 v = {0.f, 0.f, 0.f, 0.f};
      if (r0 + row < n) v = *(const float4*)(X + (size_t)(r0 + row) * D + cb);
      *(float4*)&Xt[row][cb] = v;
    }
  } else {
    const f16* X = (const f16*)Xv;
    for (int q = t; q < 64 * 16; q += 256) {
      int row = q >> 4, cb = (q & 15) << 3;
      f16x8 v = 0;
      if (r0 + row < n) v = *(const f16x8*)(X + (size_t)(r0 + row) * D + cb);
      float* xp = &Xt[row][cb];
#pragma unroll
      for (int j = 0; j < 8; ++j) xp[j] = (float)v[j];
    }
  }
  int tr = ((t >> 4) & 15) << 2;
  int tc = (t & 15) << 3;
  float acc[4][8];
#pragma unroll
  for (int i = 0; i < 4; ++i)
#pragma unroll
    for (int j = 0; j < 8; ++j) acc[i][j] = 0.f;

  for (int hh = 0; hh < 4; ++hh) {
    __syncthreads();
    for (int q = t; q < 32 * 32; q += 256) {
      int row = q >> 5, cb = (q & 31) << 2;
      *(float4*)&Wb[row][cb] = *(const float4*)(W + (size_t)(hh * 32 + row) * D + cb);
    }
    __syncthreads();
#pragma unroll 4
    for (int k = 0; k < 32; ++k) {
      float4 u0 = *(const float4*)&Wb[k][tc];
      float4 u1 = *(const float4*)&Wb[k][tc + 4];
      float bv[8] = {u0.x, u0.y, u0.z, u0.w, u1.x, u1.y, u1.z, u1.w};
      int kk = hh * 32 + k;
#pragma unroll
      for (int i = 0; i < 4; ++i) {
        float a = Xt[tr + i][kk];
#pragma unroll
        for (int j = 0; j < 8; ++j) acc[i][j] += a * bv[j];
      }
    }
  }
#pragma unroll
  for (int i = 0; i < 4; ++i) {
    int row = r0 + tr + i;
    if (row < n) {
      float s = isd[row];
      f16x8 ov;
#pragma unroll
      for (int j = 0; j < 8; ++j) ov[j] = (f16)(s * acc[i][j]);
      // slice-major store (gather operand)
      *(f16x8*)(HS + (size_t)(tc >> 4) * ss + (size_t)row * 16 + (tc & 15)) = ov;
    }
  }
}

__device__ inline f16x8 shfl_xor_f16x8(f16x8 v, int m) {
  union { f16x8 h; int i[4]; } u;
  u.h = v;
#pragma unroll
  for (int k = 0; k < 4; ++k) u.i[k] = __shfl_xor(u.i[k], m);
  return u.h;
}

// ---- sliced aggregation: G[i][s*16..] = relu(isd[i]*(sum HS_blk[s][src] + self)+b)
// block: 256 thr = 4 waves; wave: 4 nodes (16-lane groups); group: 8 edge slots
// x 2 half-rows. 32 edges in flight per iteration (4 HS + 4 csr loads/lane).
// csr is padded by 64 zeroed entries -> prefetch reads need NO clamping (index 0
// is a valid row; the guarded adds discard over-reads). slice s = blockIdx.x & 7
// (-> XCD s). Output G is ROW-MAJOR [n][128].
__global__ __launch_bounds__(256) void k_aggs(const f16* __restrict__ HS,
                                              const int* __restrict__ csr,
                                              const int* __restrict__ row_start,
                                              const int* __restrict__ deg,
                                              const float* __restrict__ isd,
                                              const float* __restrict__ bias,
                                              f16* __restrict__ G, int n) {
  const size_t ss = (size_t)n * 16;
  int t = threadIdx.x;
  int wave = t >> 6, lane = t & 63;
  int g = lane >> 4, r = lane & 15;
  int s = blockIdx.x & 7;
  int i0 = ((blockIdx.x >> 3) << 4) + (wave << 2) + g;
  bool ok = i0 < n;
  int i = ok ? i0 : n - 1;
  int hf = r & 1, er = r >> 1;
  int dg = deg[i];
  const int* cp = csr + row_start[i];  // safe reads up to cp[dg+63] (pad)
  const f16* sb = HS + (size_t)s * ss + (size_t)(hf << 3);
  f16x8 a0 = (f16x8)0, a1 = (f16x8)0, a2 = (f16x8)0, a3 = (f16x8)0;
  // csr prefetch pipeline: indices for the NEXT 32-edge window are issued
  // before the current HS loads, keeping 8 loads/lane in flight. No clamps.
  int iA = cp[er];
  int iB = cp[er + 8];
  int iC = cp[er + 16];
  int iD = cp[er + 24];
  for (int u = 0; u < dg; u += 32) {
    int cA = iA, cB = iB, cC = iC, cD = iD;
    iA = cp[u + 32 + er];
    iB = cp[u + 40 + er];
    iC = cp[u + 48 + er];
    iD = cp[u + 56 + er];
    if (u + er < dg)
      a0 += *(const f16x8*)(sb + ((size_t)(unsigned)cA << 4));
    if (u + 8 + er < dg)
      a1 += *(const f16x8*)(sb + ((size_t)(unsigned)cB << 4));
    if (u + 16 + er < dg)
      a2 += *(const f16x8*)(sb + ((size_t)(unsigned)cC << 4));
    if (u + 24 + er < dg)
      a3 += *(const f16x8*)(sb + ((size_t)(unsigned)cD << 4));
  }
  // reduce 8 edge-slots within the 16-lane group (3 levels, stays in-group)
  f16x8 tv = (a0 + a1) + (a2 + a3);
  tv += shfl_xor_f16x8(tv, 2);
  tv += shfl_xor_f16x8(tv, 4);
  tv += shfl_xor_f16x8(tv, 8);
  // epilogue: self-loop + isd + bias + relu
  f16x8 sv = *(const f16x8*)(HS + (size_t)s * ss + (size_t)i * 16 + (hf << 3));
  float di = isd[i];
  const float* bp = bias + s * 16 + (hf << 3);
  float4 b0 = *(const float4*)bp;
  float4 b1 = *(const float4*)(bp + 4);
  float bv[8] = {b0.x, b0.y, b0.z, b0.w, b1.x, b1.y, b1.z, b1.w};
  f16x8 ov;
#pragma unroll
  for (int j = 0; j < 8; ++j) {
    float v = di * ((float)tv[j] + (float)sv[j]) + bv[j];
    v = v > 0.f ? v : 0.f;
    ov[j] = (f16)v;
  }
  if (ok && r < 2)
    *(f16x8*)(G + (size_t)i * D + s * 16 + (hf << 3)) = ov;
}

// ---- classifier v3: out = H @ Wl + bl, Wl^T staged in LDS, 128 nodes/block ----
// 4 waves x 4 nodes per pass, 8 passes. Per 16-lane group: one node; lane l
// holds h[l*8..l*8+7] in regs; per class: 2 x b128 LDS (Wlt row, aligned) +
// 8 FMA + 4-shuffle butterfly; class c kept by lane c&15 in slot c>>4.
__global__ __launch_bounds__(256) void k_cls(const f16* __restrict__ H,
                                             const float* __restrict__ Wl,
                                             const float* __restrict__ bl,
                                             float* __restrict__ out, int n) {
  __shared__ float wt[N_CLS][D];  // wt[c][k] = Wl[k][c]; rows 512B -> b128 ok
  int t = threadIdx.x;
  for (int q = t; q < D * N_CLS; q += 256) {
    int k = q / N_CLS, c = q - k * N_CLS;  // consecutive q = consecutive Wl
    wt[c][k] = Wl[q];
  }
  int wv = t >> 6, lane = t & 63, g = lane >> 4, l = lane & 15;
  float bb0 = bl[l];
  float bb1 = bl[16 + l];
  float bb2 = (l < 8) ? bl[32 + l] : 0.f;
  __syncthreads();
  int node0 = (blockIdx.x << 7) + (wv << 2) + g;
  for (int it = 0; it < 8; ++it) {
    int node = node0 + it * 16;
    if (node >= n) break;  // no barriers below: divergence safe
    f16x8 h = *(const f16x8*)(H + (size_t)node * D + l * 8);
    float hf[8];
#pragma unroll
    for (int j = 0; j < 8; ++j) hf[j] = (float)h[j];
    float r0 = bb0, r1 = bb1, r2 = bb2;
#pragma unroll 4
    for (int c = 0; c < N_CLS; ++c) {
      const float* wp = &wt[c][l * 8];
      float4 w0 = *(const float4*)wp;
      float4 w1 = *(const float4*)(wp + 4);
      float p = hf[0] * w0.x + hf[1] * w0.y + hf[2] * w0.z + hf[3] * w0.w +
                hf[4] * w1.x + hf[5] * w1.y + hf[6] * w1.z + hf[7] * w1.w;
      p += __shfl_xor(p, 1);
      p += __shfl_xor(p, 2);
      p += __shfl_xor(p, 4);
      p += __shfl_xor(p, 8);
      if ((c & 15) == l) {
        if (c < 16) r0 += p;
        else if (c < 32) r1 += p;
        else r2 += p;
      }
    }
    float* op = out + (size_t)node * N_CLS;
    op[l] = r0;
    op[16 + l] = r1;
    if (l < 8) op[32 + l] = r2;
  }
}

extern "C" void kernel_launch(void* const* d_in, const int* in_sizes, int n_in,
                              void* d_out, int out_size, void* d_ws, size_t ws_size,
                              hipStream_t stream) {
  const float* x  = (const float*)d_in[0];
  const int*   ei = (const int*)d_in[1];
  const float* W1 = (const float*)d_in[2];
  const float* b1 = (const float*)d_in[3];
  const float* W2 = (const float*)d_in[4];
  const float* b2 = (const float*)d_in[5];
  const float* Wl = (const float*)d_in[6];
  const float* bl = (const float*)d_in[7];
  float* out = (float*)d_out;

  const int n = in_sizes[0] / D;  // 100000
  const int e = in_sizes[1] / 2;  // 3200000
  const int* src = ei;
  const int* dst = ei + e;
  const int nb = (n + BN - 1) / BN;  // 782

  char* ws = (char*)d_ws;
  size_t off = 0;
  auto alloc = [&](size_t bytes) -> void* {
    void* p = ws + off;
    off += (bytes + 255) & ~(size_t)255;
    return p;
  };
  int*   bcnt      = (int*)alloc(NBMAX * 4);
  int*   bbase     = (int*)alloc(NBMAX * 4);
  int*   bcur      = (int*)alloc(NBMAX * 4);
  int*   deg       = (int*)alloc((size_t)n * 4);
  int*   row_start = (int*)alloc((size_t)n * 4);
  float* isd       = (float*)alloc((size_t)n * 4);
  int*   csr       = (int*)alloc(((size_t)e + 64) * 4);  // +64 pad: clamp-free prefetch
  f16*   hA        = (f16*)alloc((size_t)n * D * 2);
  f16*   hB        = (f16*)alloc((size_t)n * D * 2);
  unsigned int* binned = (unsigned int*)hA;  // dead before gemm1 writes hA

  hipMemsetAsync(bcnt, 0, NBMAX * 4, stream);
  hipMemsetAsync(csr + e, 0, 64 * 4, stream);  // pad -> valid index 0

  const int nwg_place = 512;
  k_hist<<<1024, 256, 0, stream>>>(dst, bcnt, e);
  k_bscan<<<1, 1024, 0, stream>>>(bcnt, bbase, bcur);
  k_place<<<nwg_place, 256, 0, stream>>>(src, dst, bcur, binned, e, nwg_place);
  k_csr<<<nb, 256, 0, stream>>>(binned, bbase, csr, deg, isd, row_start, n);

  int gblocks = (n + 63) / 64;
  int ablocks = ((n + 15) / 16) * 8;  // node-groups x 8 slices (grid % 8 == 0)
  // layer 1: gemm -> slice-major hA; agg -> row-major hB
  k_gemm_t<false><<<gblocks, 256, 0, stream>>>(x, W1, isd, hA, n);
  k_aggs<<<ablocks, 256, 0, stream>>>(hA, csr, row_start, deg, isd, b1, hB, n);
  // layer 2: gemm (row-major in) -> slice-major hA; agg -> row-major hB
  k_gemm_t<true><<<gblocks, 256, 0, stream>>>(hB, W2, isd, hA, n);
  k_aggs<<<ablocks, 256, 0, stream>>>(hA, csr, row_start, deg, isd, b2, hB, n);
  // classifier
  k_cls<<<(n + 127) / 128, 256, 0, stream>>>(hB, Wl, bl, out, n);
}

// Round 7
// 657.850 us; speedup vs baseline: 1.5544x; 1.0549x over previous
//
#include <hip/hip_runtime.h>
#include <hip/hip_bf16.h>

typedef _Float16 f16;
typedef _Float16 f16x4 __attribute__((ext_vector_type(4)));
typedef _Float16 f16x8 __attribute__((ext_vector_type(8)));
typedef float f32x4 __attribute__((ext_vector_type(4)));

#define D 128
#define N_CLS 40
#define BN 128       // nodes per bucket
#define NBMAX 1024   // padded bucket count

// Gather operand (GEMM output) is feature-sliced: 8 slices x 16 feats (32B/row),
// slice-major: HS_blk[s][i][f], elem offset = s*(n*16) + i*16 + f.
// Slice s is processed only by blocks with blockIdx.x%8==s -> XCD s (round-robin
// dispatch) -> per-XCD gather working set = n*32B = 3.2MB < 4MB L2. [confirmed
// round 2: agg FETCH_SIZE 363MB -> 74MB]
// Aggregation OUTPUT is row-major (consumed densely by GEMM2 / classifier).
// Preprocessing: bucket-major two-stage scatter (random writes confined to
// 16KB L1-resident windows). [round 4: the one-pass alternative = 194MB
// write-allocate, 321us]

// ---- 1. bucket histogram of dst (LDS-staged) ----
__global__ __launch_bounds__(256) void k_hist(const int* __restrict__ dst,
                                              int* __restrict__ bcnt, int e) {
  __shared__ int lh[NBMAX];
  for (int j = threadIdx.x; j < NBMAX; j += 256) lh[j] = 0;
  __syncthreads();
  int stride = gridDim.x * blockDim.x;
  for (int q = blockIdx.x * blockDim.x + threadIdx.x; q < e; q += stride)
    atomicAdd(&lh[dst[q] >> 7], 1);
  __syncthreads();
  for (int j = threadIdx.x; j < NBMAX; j += 256)
    if (lh[j]) atomicAdd(&bcnt[j], lh[j]);
}

// ---- 2. exclusive scan of bucket counts ----
__global__ __launch_bounds__(1024) void k_bscan(const int* __restrict__ bcnt,
                                                int* __restrict__ bbase,
                                                int* __restrict__ bcur) {
  __shared__ int sums[NBMAX];
  int t = threadIdx.x;
  int c = bcnt[t];
  sums[t] = c;
  __syncthreads();
  for (int off = 1; off < NBMAX; off <<= 1) {
    int a = (t >= off) ? sums[t - off] : 0;
    __syncthreads();
    sums[t] += a;
    __syncthreads();
  }
  bbase[t] = sums[t] - c;
  bcur[t] = sums[t] - c;
}

// ---- 3. bin edges into bucket-major order ----
__global__ __launch_bounds__(256) void k_place(const int* __restrict__ src,
                                               const int* __restrict__ dst,
                                               int* __restrict__ bcur,
                                               unsigned int* __restrict__ binned,
                                               int e, int nwg) {
  __shared__ int lh[NBMAX];
  __shared__ int lofs[NBMAX];
  __shared__ int lcur[NBMAX];
  int chunk = (e + nwg - 1) / nwg;
  int lo = blockIdx.x * chunk;
  int hi = min(e, lo + chunk);
  int t = threadIdx.x;
  for (int j = t; j < NBMAX; j += 256) { lh[j] = 0; lcur[j] = 0; }
  __syncthreads();
  for (int q = lo + t; q < hi; q += 256) atomicAdd(&lh[dst[q] >> 7], 1);
  __syncthreads();
  for (int j = t; j < NBMAX; j += 256) {
    int c = lh[j];
    lofs[j] = c ? atomicAdd(&bcur[j], c) : 0;
  }
  __syncthreads();
  for (int q = lo + t; q < hi; q += 256) {
    int d = dst[q];
    int b = d >> 7;
    int r = atomicAdd(&lcur[b], 1);
    binned[lofs[b] + r] = ((unsigned int)(d & 127) << 17) | (unsigned int)src[q];
  }
}

// ---- 4. per-bucket counting sort -> CSR + deg + isd + row_start ----
__global__ __launch_bounds__(256) void k_csr(const unsigned int* __restrict__ binned,
                                             const int* __restrict__ bbase,
                                             int* __restrict__ csr,
                                             int* __restrict__ deg,
                                             float* __restrict__ isd,
                                             int* __restrict__ row_start, int n) {
  int b = blockIdx.x;
  int lo = bbase[b], hi = bbase[b + 1];
  __shared__ int h[BN];
  __shared__ int sc[BN];
  __shared__ int cur[BN];
  int t = threadIdx.x;
  if (t < BN) h[t] = 0;
  __syncthreads();
  for (int q = lo + t; q < hi; q += 256) atomicAdd(&h[binned[q] >> 17], 1);
  __syncthreads();
  if (t < BN) sc[t] = h[t];
  __syncthreads();
  for (int off = 1; off < BN; off <<= 1) {
    int a = 0;
    if (t < BN && t >= off) a = sc[t - off];
    __syncthreads();
    if (t < BN) sc[t] += a;
    __syncthreads();
  }
  if (t < BN) {
    int excl = sc[t] - h[t];
    cur[t] = lo + excl;
    int i = b * BN + t;
    if (i < n) {
      deg[i] = h[t];
      isd[i] = rsqrtf((float)(h[t] + 1));
      row_start[i] = lo + excl;
    }
  }
  __syncthreads();
  for (int q = lo + t; q < hi; q += 256) {
    unsigned int u = binned[q];
    int p = atomicAdd(&cur[u >> 17], 1);
    csr[p] = (int)(u & 0x1FFFF);
  }
}

// ---- MFMA GEMM: HS_blk = isd[i] * (X @ W), f16 inputs, fp32 accum ----
// Block: 256 thr = 4 waves, 64 rows x 128 cols, K=128 in 4 steps of 32.
// Wave w: rows w*16..w*16+15; 8 col-tiles of 16 (= 8 output slices).
// A frag: lane l holds A[row=l&15][k = ks*32 + (l>>4)*8 + j]   (16B LDS read)
// B frag: lane l holds W[k = ks*32 + (l>>4)*8 + j][col=ct*16 + (l&15)]
//         -> staged transposed Wt[c][k] so the read is 16B contiguous.
// C/D (guide-verified m89): col = lane&15, row = (lane>>4)*4 + reg.
// LDS rows padded to 136 f16 = 272B (16B-aligned, breaks pow2 banks).
template <bool HALF_IN>
__global__ __launch_bounds__(256) void k_gemm_m(const void* __restrict__ Xv,
                                                const float* __restrict__ W,
                                                const float* __restrict__ isd,
                                                f16* __restrict__ HS, int n) {
  __shared__ f16 At[64][136];
  __shared__ f16 Wt[128][136];
  const size_t ss = (size_t)n * 16;  // slice stride in f16 elems
  int t = threadIdx.x;
  int r0 = blockIdx.x * 64;
  // stage A (64 rows x 128 k) as f16
  if (!HALF_IN) {
    const float* X = (const float*)Xv;
    for (int q = t; q < 64 * 32; q += 256) {
      int row = q >> 5, cb = (q & 31) << 2;
      float4 v = {0.f, 0.f, 0.f, 0.f};
      if (r0 + row < n) v = *(const float4*)(X + (size_t)(r0 + row) * D + cb);
      f16x4 h = {(f16)v.x, (f16)v.y, (f16)v.z, (f16)v.w};
      *(f16x4*)&At[row][cb] = h;
    }
  } else {
    const f16* X = (const f16*)Xv;
    for (int q = t; q < 64 * 16; q += 256) {
      int row = q >> 4, cb = (q & 15) << 3;
      f16x8 v = 0;
      if (r0 + row < n) v = *(const f16x8*)(X + (size_t)(r0 + row) * D + cb);
      *(f16x8*)&At[row][cb] = v;
    }
  }
  // stage W transposed as f16: Wt[c][k] = W[k*128+c] (coalesced global reads)
  for (int q = t; q < D * D; q += 256) {
    int k = q >> 7, c = q & 127;
    Wt[c][k] = (f16)W[q];
  }
  __syncthreads();

  int wave = t >> 6, lane = t & 63;
  int lw = lane & 15, kg = lane >> 4;
  f32x4 acc[8];
#pragma unroll
  for (int ct = 0; ct < 8; ++ct) acc[ct] = (f32x4)0.f;
#pragma unroll
  for (int ks = 0; ks < 4; ++ks) {
    f16x8 af = *(const f16x8*)&At[(wave << 4) + lw][ks * 32 + kg * 8];
#pragma unroll
    for (int ct = 0; ct < 8; ++ct) {
      f16x8 bf = *(const f16x8*)&Wt[ct * 16 + lw][ks * 32 + kg * 8];
      acc[ct] = __builtin_amdgcn_mfma_f32_16x16x32_f16(af, bf, acc[ct], 0, 0, 0);
    }
  }
  // epilogue: scale by isd, store slice-major f16 (slice == col-tile)
  int rbase = r0 + (wave << 4) + (kg << 2);
  float sv[4];
#pragma unroll
  for (int rr = 0; rr < 4; ++rr)
    sv[rr] = (rbase + rr < n) ? isd[rbase + rr] : 0.f;
#pragma unroll
  for (int ct = 0; ct < 8; ++ct) {
#pragma unroll
    for (int rr = 0; rr < 4; ++rr) {
      int node = rbase + rr;
      if (node < n)
        HS[(size_t)ct * ss + (size_t)node * 16 + lw] = (f16)(acc[ct][rr] * sv[rr]);
    }
  }
}

__device__ inline f16x8 shfl_xor_f16x8(f16x8 v, int m) {
  union { f16x8 h; int i[4]; } u;
  u.h = v;
#pragma unroll
  for (int k = 0; k < 4; ++k) u.i[k] = __shfl_xor(u.i[k], m);
  return u.h;
}

// ---- sliced aggregation: G[i][s*16..] = relu(isd[i]*(sum HS_blk[s][src] + self)+b)
// block: 256 thr = 4 waves; wave: 4 nodes (16-lane groups); group: 8 edge slots
// x 2 half-rows, unroll 2 (16 edges/iter/node). Wave-uniform SGPR base +
// 32-bit voffset -> saddr addressing. csr padded 64 -> clamp-free prefetch.
// slice s = blockIdx.x & 7 (-> XCD s). Output G is ROW-MAJOR [n][128].
__global__ __launch_bounds__(256) void k_aggs(const f16* __restrict__ HS,
                                              const int* __restrict__ csr,
                                              const int* __restrict__ row_start,
                                              const int* __restrict__ deg,
                                              const float* __restrict__ bias,
                                              f16* __restrict__ G, int n) {
  const size_t ss = (size_t)n * 16;
  int t = threadIdx.x;
  int wave = t >> 6, lane = t & 63;
  int g = lane >> 4, r = lane & 15;
  int s = blockIdx.x & 7;
  int i0 = ((blockIdx.x >> 3) << 4) + (wave << 2) + g;
  bool ok = i0 < n;
  int i = ok ? i0 : n - 1;
  int hf = r & 1, er = r >> 1;
  int dg = deg[i];
  const int* cp = csr + row_start[i];           // safe reads: +64 pad
  const char* sbase = (const char*)(HS + (size_t)s * ss);  // wave-uniform
  unsigned hofs = (unsigned)(hf << 4);
  f16x8 a0 = (f16x8)0, a1 = (f16x8)0;
  int iA = cp[er];
  int iB = cp[er + 8];
  for (int u = 0; u < dg; u += 16) {
    unsigned oA = ((unsigned)iA << 5) + hofs;
    unsigned oB = ((unsigned)iB << 5) + hofs;
    iA = cp[u + 16 + er];
    iB = cp[u + 24 + er];
    if (u + er < dg)
      a0 += *(const f16x8*)(sbase + oA);
    if (u + 8 + er < dg)
      a1 += *(const f16x8*)(sbase + oB);
  }
  // reduce 8 edge-slots within the 16-lane group (3 levels, stays in-group)
  f16x8 tv = a0 + a1;
  tv += shfl_xor_f16x8(tv, 2);
  tv += shfl_xor_f16x8(tv, 4);
  tv += shfl_xor_f16x8(tv, 8);
  // epilogue: self-loop + isd + bias + relu
  f16x8 svv = *(const f16x8*)(sbase + ((unsigned)i << 5) + hofs);
  float di = rsqrtf((float)(dg + 1));  // == isd[i] (same rsqrt path as k_csr)
  const float* bp = bias + s * 16 + (hf << 3);
  float4 b0 = *(const float4*)bp;
  float4 b1 = *(const float4*)(bp + 4);
  float bv[8] = {b0.x, b0.y, b0.z, b0.w, b1.x, b1.y, b1.z, b1.w};
  f16x8 ov;
#pragma unroll
  for (int j = 0; j < 8; ++j) {
    float v = di * ((float)tv[j] + (float)svv[j]) + bv[j];
    v = v > 0.f ? v : 0.f;
    ov[j] = (f16)v;
  }
  if (ok && r < 2)
    *(f16x8*)(G + (size_t)i * D + s * 16 + (hf << 3)) = ov;
}

// ---- classifier v3: out = H @ Wl + bl, Wl^T staged in LDS, 128 nodes/block ----
__global__ __launch_bounds__(256) void k_cls(const f16* __restrict__ H,
                                             const float* __restrict__ Wl,
                                             const float* __restrict__ bl,
                                             float* __restrict__ out, int n) {
  __shared__ float wt[N_CLS][D];  // wt[c][k] = Wl[k][c]; rows 512B -> b128 ok
  int t = threadIdx.x;
  for (int q = t; q < D * N_CLS; q += 256) {
    int k = q / N_CLS, c = q - k * N_CLS;  // consecutive q = consecutive Wl
    wt[c][k] = Wl[q];
  }
  int wv = t >> 6, lane = t & 63, g = lane >> 4, l = lane & 15;
  float bb0 = bl[l];
  float bb1 = bl[16 + l];
  float bb2 = (l < 8) ? bl[32 + l] : 0.f;
  __syncthreads();
  int node0 = (blockIdx.x << 7) + (wv << 2) + g;
  for (int it = 0; it < 8; ++it) {
    int node = node0 + it * 16;
    if (node >= n) break;  // no barriers below: divergence safe
    f16x8 h = *(const f16x8*)(H + (size_t)node * D + l * 8);
    float hf[8];
#pragma unroll
    for (int j = 0; j < 8; ++j) hf[j] = (float)h[j];
    float r0 = bb0, r1 = bb1, r2 = bb2;
#pragma unroll 4
    for (int c = 0; c < N_CLS; ++c) {
      const float* wp = &wt[c][l * 8];
      float4 w0 = *(const float4*)wp;
      float4 w1 = *(const float4*)(wp + 4);
      float p = hf[0] * w0.x + hf[1] * w0.y + hf[2] * w0.z + hf[3] * w0.w +
                hf[4] * w1.x + hf[5] * w1.y + hf[6] * w1.z + hf[7] * w1.w;
      p += __shfl_xor(p, 1);
      p += __shfl_xor(p, 2);
      p += __shfl_xor(p, 4);
      p += __shfl_xor(p, 8);
      if ((c & 15) == l) {
        if (c < 16) r0 += p;
        else if (c < 32) r1 += p;
        else r2 += p;
      }
    }
    float* op = out + (size_t)node * N_CLS;
    op[l] = r0;
    op[16 + l] = r1;
    if (l < 8) op[32 + l] = r2;
  }
}

extern "C" void kernel_launch(void* const* d_in, const int* in_sizes, int n_in,
                              void* d_out, int out_size, void* d_ws, size_t ws_size,
                              hipStream_t stream) {
  const float* x  = (const float*)d_in[0];
  const int*   ei = (const int*)d_in[1];
  const float* W1 = (const float*)d_in[2];
  const float* b1 = (const float*)d_in[3];
  const float* W2 = (const float*)d_in[4];
  const float* b2 = (const float*)d_in[5];
  const float* Wl = (const float*)d_in[6];
  const float* bl = (const float*)d_in[7];
  float* out = (float*)d_out;

  const int n = in_sizes[0] / D;  // 100000
  const int e = in_sizes[1] / 2;  // 3200000
  const int* src = ei;
  const int* dst = ei + e;
  const int nb = (n + BN - 1) / BN;  // 782

  char* ws = (char*)d_ws;
  size_t off = 0;
  auto alloc = [&](size_t bytes) -> void* {
    void* p = ws + off;
    off += (bytes + 255) & ~(size_t)255;
    return p;
  };
  int*   bcnt      = (int*)alloc(NBMAX * 4);
  int*   bbase     = (int*)alloc(NBMAX * 4);
  int*   bcur      = (int*)alloc(NBMAX * 4);
  int*   deg       = (int*)alloc((size_t)n * 4);
  int*   row_start = (int*)alloc((size_t)n * 4);
  float* isd       = (float*)alloc((size_t)n * 4);
  int*   csr       = (int*)alloc(((size_t)e + 64) * 4);  // +64 pad: clamp-free
  f16*   hA        = (f16*)alloc((size_t)n * D * 2);
  f16*   hB        = (f16*)alloc((size_t)n * D * 2);
  unsigned int* binned = (unsigned int*)hA;  // dead before gemm1 writes hA

  hipMemsetAsync(bcnt, 0, NBMAX * 4, stream);
  hipMemsetAsync(csr + e, 0, 64 * 4, stream);  // pad -> valid index 0

  const int nwg_place = 512;
  k_hist<<<1024, 256, 0, stream>>>(dst, bcnt, e);
  k_bscan<<<1, 1024, 0, stream>>>(bcnt, bbase, bcur);
  k_place<<<nwg_place, 256, 0, stream>>>(src, dst, bcur, binned, e, nwg_place);
  k_csr<<<nb, 256, 0, stream>>>(binned, bbase, csr, deg, isd, row_start, n);

  int gblocks = (n + 63) / 64;
  int ablocks = ((n + 15) / 16) * 8;  // node-groups x 8 slices (grid % 8 == 0)
  // layer 1: MFMA gemm -> slice-major hA; agg -> row-major hB
  k_gemm_m<false><<<gblocks, 256, 0, stream>>>(x, W1, isd, hA, n);
  k_aggs<<<ablocks, 256, 0, stream>>>(hA, csr, row_start, deg, b1, hB, n);
  // layer 2: MFMA gemm (row-major f16 in) -> slice-major hA; agg -> row-major hB
  k_gemm_m<true><<<gblocks, 256, 0, stream>>>(hB, W2, isd, hA, n);
  k_aggs<<<ablocks, 256, 0, stream>>>(hA, csr, row_start, deg, b2, hB, n);
  // classifier
  k_cls<<<(n + 127) / 128, 256, 0, stream>>>(hB, Wl, bl, out, n);
}

// Round 8
// 646.273 us; speedup vs baseline: 1.5823x; 1.0179x over previous
//
#include <hip/hip_runtime.h>
#include <hip/hip_bf16.h>

typedef _Float16 f16;
typedef _Float16 f16x4 __attribute__((ext_vector_type(4)));
typedef _Float16 f16x8 __attribute__((ext_vector_type(8)));
typedef float f32x4 __attribute__((ext_vector_type(4)));

#define D 128
#define N_CLS 40
#define BN 128       // nodes per bucket
#define NBMAX 1024   // padded bucket count

// Gather operand (GEMM output) is feature-sliced: 4 slices x 32 feats = 64B/row,
// slice-major: HS_blk[s][i][f], f in [0,32). 64B rows mean every L1 miss
// delivers a fully-used cache line (H-MSHR model: agg throughput = MSHR-limited
// miss rate; 32B rows wasted half of every line). Per-XCD working set is
// n*64B = 6.4MB (>4MB L2 -> ~62% L2 hit, rest served by 256MB L3; the miss
// count halves, which dominates). slice = blockIdx&3; XCD x serves slice x&3.
// Aggregation OUTPUT is row-major (consumed densely by GEMM2 / classifier).
// Preprocessing: bucket-major two-stage scatter (random writes confined to
// 16KB L1-resident windows). [round 4: one-pass alternative = 194MB
// write-allocate, 321us]

// ---- 1. bucket histogram of dst (LDS-staged) ----
__global__ __launch_bounds__(256) void k_hist(const int* __restrict__ dst,
                                              int* __restrict__ bcnt, int e) {
  __shared__ int lh[NBMAX];
  for (int j = threadIdx.x; j < NBMAX; j += 256) lh[j] = 0;
  __syncthreads();
  int stride = gridDim.x * blockDim.x;
  for (int q = blockIdx.x * blockDim.x + threadIdx.x; q < e; q += stride)
    atomicAdd(&lh[dst[q] >> 7], 1);
  __syncthreads();
  for (int j = threadIdx.x; j < NBMAX; j += 256)
    if (lh[j]) atomicAdd(&bcnt[j], lh[j]);
}

// ---- 2. exclusive scan of bucket counts ----
__global__ __launch_bounds__(1024) void k_bscan(const int* __restrict__ bcnt,
                                                int* __restrict__ bbase,
                                                int* __restrict__ bcur) {
  __shared__ int sums[NBMAX];
  int t = threadIdx.x;
  int c = bcnt[t];
  sums[t] = c;
  __syncthreads();
  for (int off = 1; off < NBMAX; off <<= 1) {
    int a = (t >= off) ? sums[t - off] : 0;
    __syncthreads();
    sums[t] += a;
    __syncthreads();
  }
  bbase[t] = sums[t] - c;
  bcur[t] = sums[t] - c;
}

// ---- 3. bin edges into bucket-major order ----
__global__ __launch_bounds__(256) void k_place(const int* __restrict__ src,
                                               const int* __restrict__ dst,
                                               int* __restrict__ bcur,
                                               unsigned int* __restrict__ binned,
                                               int e, int nwg) {
  __shared__ int lh[NBMAX];
  __shared__ int lofs[NBMAX];
  __shared__ int lcur[NBMAX];
  int chunk = (e + nwg - 1) / nwg;
  int lo = blockIdx.x * chunk;
  int hi = min(e, lo + chunk);
  int t = threadIdx.x;
  for (int j = t; j < NBMAX; j += 256) { lh[j] = 0; lcur[j] = 0; }
  __syncthreads();
  for (int q = lo + t; q < hi; q += 256) atomicAdd(&lh[dst[q] >> 7], 1);
  __syncthreads();
  for (int j = t; j < NBMAX; j += 256) {
    int c = lh[j];
    lofs[j] = c ? atomicAdd(&bcur[j], c) : 0;
  }
  __syncthreads();
  for (int q = lo + t; q < hi; q += 256) {
    int d = dst[q];
    int b = d >> 7;
    int r = atomicAdd(&lcur[b], 1);
    binned[lofs[b] + r] = ((unsigned int)(d & 127) << 17) | (unsigned int)src[q];
  }
}

// ---- 4. per-bucket counting sort -> CSR + deg + isd + row_start ----
__global__ __launch_bounds__(256) void k_csr(const unsigned int* __restrict__ binned,
                                             const int* __restrict__ bbase,
                                             int* __restrict__ csr,
                                             int* __restrict__ deg,
                                             float* __restrict__ isd,
                                             int* __restrict__ row_start, int n) {
  int b = blockIdx.x;
  int lo = bbase[b], hi = bbase[b + 1];
  __shared__ int h[BN];
  __shared__ int sc[BN];
  __shared__ int cur[BN];
  int t = threadIdx.x;
  if (t < BN) h[t] = 0;
  __syncthreads();
  for (int q = lo + t; q < hi; q += 256) atomicAdd(&h[binned[q] >> 17], 1);
  __syncthreads();
  if (t < BN) sc[t] = h[t];
  __syncthreads();
  for (int off = 1; off < BN; off <<= 1) {
    int a = 0;
    if (t < BN && t >= off) a = sc[t - off];
    __syncthreads();
    if (t < BN) sc[t] += a;
    __syncthreads();
  }
  if (t < BN) {
    int excl = sc[t] - h[t];
    cur[t] = lo + excl;
    int i = b * BN + t;
    if (i < n) {
      deg[i] = h[t];
      isd[i] = rsqrtf((float)(h[t] + 1));
      row_start[i] = lo + excl;
    }
  }
  __syncthreads();
  for (int q = lo + t; q < hi; q += 256) {
    unsigned int u = binned[q];
    int p = atomicAdd(&cur[u >> 17], 1);
    csr[p] = (int)(u & 0x1FFFF);
  }
}

// ---- MFMA GEMM: HS_blk = isd[i] * (X @ W), f16 inputs, fp32 accum ----
// Block: 256 thr = 4 waves, 64 rows x 128 cols, K=128 in 4 steps of 32.
// C/D (guide-verified m89): col = lane&15, row = (lane>>4)*4 + reg.
// Output slice-major 4 x 32 feats: col -> slice ct>>1, within (ct&1)*16 + lw.
template <bool HALF_IN>
__global__ __launch_bounds__(256) void k_gemm_m(const void* __restrict__ Xv,
                                                const float* __restrict__ W,
                                                const float* __restrict__ isd,
                                                f16* __restrict__ HS, int n) {
  __shared__ f16 At[64][136];
  __shared__ f16 Wt[128][136];
  const size_t ss = (size_t)n * 32;  // slice stride in f16 elems (4x32 layout)
  int t = threadIdx.x;
  int r0 = blockIdx.x * 64;
  // stage A (64 rows x 128 k) as f16
  if (!HALF_IN) {
    const float* X = (const float*)Xv;
    for (int q = t; q < 64 * 32; q += 256) {
      int row = q >> 5, cb = (q & 31) << 2;
      float4 v = {0.f, 0.f, 0.f, 0.f};
      if (r0 + row < n) v = *(const float4*)(X + (size_t)(r0 + row) * D + cb);
      f16x4 h = {(f16)v.x, (f16)v.y, (f16)v.z, (f16)v.w};
      *(f16x4*)&At[row][cb] = h;
    }
  } else {
    const f16* X = (const f16*)Xv;
    for (int q = t; q < 64 * 16; q += 256) {
      int row = q >> 4, cb = (q & 15) << 3;
      f16x8 v = 0;
      if (r0 + row < n) v = *(const f16x8*)(X + (size_t)(r0 + row) * D + cb);
      *(f16x8*)&At[row][cb] = v;
    }
  }
  // stage W transposed as f16 (float4-vectorized): Wt[c][k] = W[k*128+c]
  for (int q = t; q < (D * D) / 4; q += 256) {
    int k = q >> 5, cq = (q & 31) << 2;
    float4 w = *(const float4*)(W + (size_t)k * D + cq);
    Wt[cq + 0][k] = (f16)w.x;
    Wt[cq + 1][k] = (f16)w.y;
    Wt[cq + 2][k] = (f16)w.z;
    Wt[cq + 3][k] = (f16)w.w;
  }
  __syncthreads();

  int wave = t >> 6, lane = t & 63;
  int lw = lane & 15, kg = lane >> 4;
  f32x4 acc[8];
#pragma unroll
  for (int ct = 0; ct < 8; ++ct) acc[ct] = (f32x4)0.f;
#pragma unroll
  for (int ks = 0; ks < 4; ++ks) {
    f16x8 af = *(const f16x8*)&At[(wave << 4) + lw][ks * 32 + kg * 8];
#pragma unroll
    for (int ct = 0; ct < 8; ++ct) {
      f16x8 bf = *(const f16x8*)&Wt[ct * 16 + lw][ks * 32 + kg * 8];
      acc[ct] = __builtin_amdgcn_mfma_f32_16x16x32_f16(af, bf, acc[ct], 0, 0, 0);
    }
  }
  // epilogue: scale by isd, store slice-major f16 (4 slices of 32)
  int rbase = r0 + (wave << 4) + (kg << 2);
  float sv[4];
#pragma unroll
  for (int rr = 0; rr < 4; ++rr)
    sv[rr] = (rbase + rr < n) ? isd[rbase + rr] : 0.f;
#pragma unroll
  for (int ct = 0; ct < 8; ++ct) {
#pragma unroll
    for (int rr = 0; rr < 4; ++rr) {
      int node = rbase + rr;
      if (node < n)
        HS[(size_t)(ct >> 1) * ss + (size_t)node * 32 + ((ct & 1) << 4) + lw] =
            (f16)(acc[ct][rr] * sv[rr]);
    }
  }
}

__device__ inline f16x8 shfl_xor_f16x8(f16x8 v, int m) {
  union { f16x8 h; int i[4]; } u;
  u.h = v;
#pragma unroll
  for (int k = 0; k < 4; ++k) u.i[k] = __shfl_xor(u.i[k], m);
  return u.h;
}

// ---- sliced aggregation (4 slices x 32 feats, 64B rows) ----
// G[i][s*32..] = relu(isd[i]*(sum HS_blk[s][src] + self) + b)
// block: 256 thr = 4 waves; wave: 4 nodes (16-lane groups); group: 4 edge
// slots (er = r>>2) x 4 row-quarters (q = r&3, 16B each). 16 edges/iter via 4
// loads; each edge row = one fully-used 64B line. csr padded 64 ->
// clamp-free prefetch. slice s = blockIdx&3 (XCD x -> slice x&3).
// Output G is ROW-MAJOR [n][128].
__global__ __launch_bounds__(256) void k_aggs(const f16* __restrict__ HS,
                                              const int* __restrict__ csr,
                                              const int* __restrict__ row_start,
                                              const int* __restrict__ deg,
                                              const float* __restrict__ bias,
                                              f16* __restrict__ G, int n) {
  const size_t ss = (size_t)n * 32;
  int t = threadIdx.x;
  int wave = t >> 6, lane = t & 63;
  int g = lane >> 4, r = lane & 15;
  int s = blockIdx.x & 3;
  int i0 = ((blockIdx.x >> 2) << 4) + (wave << 2) + g;
  bool ok = i0 < n;
  int i = ok ? i0 : n - 1;
  int q = r & 3, er = r >> 2;
  int dg = deg[i];
  const int* cp = csr + row_start[i];           // safe reads: +64 pad
  const char* sbase = (const char*)(HS + (size_t)s * ss);  // wave-uniform
  unsigned qofs = (unsigned)(q << 4);
  f16x8 a0 = (f16x8)0, a1 = (f16x8)0, a2 = (f16x8)0, a3 = (f16x8)0;
  int iA = cp[er];
  int iB = cp[er + 4];
  int iC = cp[er + 8];
  int iD = cp[er + 12];
  for (int u = 0; u < dg; u += 16) {
    unsigned oA = ((unsigned)iA << 6) + qofs;
    unsigned oB = ((unsigned)iB << 6) + qofs;
    unsigned oC = ((unsigned)iC << 6) + qofs;
    unsigned oD = ((unsigned)iD << 6) + qofs;
    iA = cp[u + 16 + er];
    iB = cp[u + 20 + er];
    iC = cp[u + 24 + er];
    iD = cp[u + 28 + er];
    if (u + er < dg)
      a0 += *(const f16x8*)(sbase + oA);
    if (u + 4 + er < dg)
      a1 += *(const f16x8*)(sbase + oB);
    if (u + 8 + er < dg)
      a2 += *(const f16x8*)(sbase + oC);
    if (u + 12 + er < dg)
      a3 += *(const f16x8*)(sbase + oD);
  }
  // reduce the 4 edge slots (lanes with same q differ in bits 2,3)
  f16x8 tv = (a0 + a1) + (a2 + a3);
  tv += shfl_xor_f16x8(tv, 4);
  tv += shfl_xor_f16x8(tv, 8);
  // epilogue: self-loop + isd + bias + relu
  f16x8 svv = *(const f16x8*)(sbase + ((unsigned)i << 6) + qofs);
  float di = rsqrtf((float)(dg + 1));  // == isd[i] (same rsqrt path as k_csr)
  const float* bp = bias + s * 32 + (q << 3);
  float4 b0 = *(const float4*)bp;
  float4 b1 = *(const float4*)(bp + 4);
  float bv[8] = {b0.x, b0.y, b0.z, b0.w, b1.x, b1.y, b1.z, b1.w};
  f16x8 ov;
#pragma unroll
  for (int j = 0; j < 8; ++j) {
    float v = di * ((float)tv[j] + (float)svv[j]) + bv[j];
    v = v > 0.f ? v : 0.f;
    ov[j] = (f16)v;
  }
  if (ok && er == 0)
    *(f16x8*)(G + (size_t)i * D + s * 32 + (q << 3)) = ov;
}

// ---- classifier v3: out = H @ Wl + bl, Wl^T staged in LDS, 128 nodes/block ----
__global__ __launch_bounds__(256) void k_cls(const f16* __restrict__ H,
                                             const float* __restrict__ Wl,
                                             const float* __restrict__ bl,
                                             float* __restrict__ out, int n) {
  __shared__ float wt[N_CLS][D];  // wt[c][k] = Wl[k][c]; rows 512B -> b128 ok
  int t = threadIdx.x;
  for (int q = t; q < D * N_CLS; q += 256) {
    int k = q / N_CLS, c = q - k * N_CLS;  // consecutive q = consecutive Wl
    wt[c][k] = Wl[q];
  }
  int wv = t >> 6, lane = t & 63, g = lane >> 4, l = lane & 15;
  float bb0 = bl[l];
  float bb1 = bl[16 + l];
  float bb2 = (l < 8) ? bl[32 + l] : 0.f;
  __syncthreads();
  int node0 = (blockIdx.x << 7) + (wv << 2) + g;
  for (int it = 0; it < 8; ++it) {
    int node = node0 + it * 16;
    if (node >= n) break;  // no barriers below: divergence safe
    f16x8 h = *(const f16x8*)(H + (size_t)node * D + l * 8);
    float hf[8];
#pragma unroll
    for (int j = 0; j < 8; ++j) hf[j] = (float)h[j];
    float r0 = bb0, r1 = bb1, r2 = bb2;
#pragma unroll 4
    for (int c = 0; c < N_CLS; ++c) {
      const float* wp = &wt[c][l * 8];
      float4 w0 = *(const float4*)wp;
      float4 w1 = *(const float4*)(wp + 4);
      float p = hf[0] * w0.x + hf[1] * w0.y + hf[2] * w0.z + hf[3] * w0.w +
                hf[4] * w1.x + hf[5] * w1.y + hf[6] * w1.z + hf[7] * w1.w;
      p += __shfl_xor(p, 1);
      p += __shfl_xor(p, 2);
      p += __shfl_xor(p, 4);
      p += __shfl_xor(p, 8);
      if ((c & 15) == l) {
        if (c < 16) r0 += p;
        else if (c < 32) r1 += p;
        else r2 += p;
      }
    }
    float* op = out + (size_t)node * N_CLS;
    op[l] = r0;
    op[16 + l] = r1;
    if (l < 8) op[32 + l] = r2;
  }
}

extern "C" void kernel_launch(void* const* d_in, const int* in_sizes, int n_in,
                              void* d_out, int out_size, void* d_ws, size_t ws_size,
                              hipStream_t stream) {
  const float* x  = (const float*)d_in[0];
  const int*   ei = (const int*)d_in[1];
  const float* W1 = (const float*)d_in[2];
  const float* b1 = (const float*)d_in[3];
  const float* W2 = (const float*)d_in[4];
  const float* b2 = (const float*)d_in[5];
  const float* Wl = (const float*)d_in[6];
  const float* bl = (const float*)d_in[7];
  float* out = (float*)d_out;

  const int n = in_sizes[0] / D;  // 100000
  const int e = in_sizes[1] / 2;  // 3200000
  const int* src = ei;
  const int* dst = ei + e;
  const int nb = (n + BN - 1) / BN;  // 782

  char* ws = (char*)d_ws;
  size_t off = 0;
  auto alloc = [&](size_t bytes) -> void* {
    void* p = ws + off;
    off += (bytes + 255) & ~(size_t)255;
    return p;
  };
  int*   bcnt      = (int*)alloc(NBMAX * 4);
  int*   bbase     = (int*)alloc(NBMAX * 4);
  int*   bcur      = (int*)alloc(NBMAX * 4);
  int*   deg       = (int*)alloc((size_t)n * 4);
  int*   row_start = (int*)alloc((size_t)n * 4);
  float* isd       = (float*)alloc((size_t)n * 4);
  int*   csr       = (int*)alloc(((size_t)e + 64) * 4);  // +64 pad: clamp-free
  f16*   hA        = (f16*)alloc((size_t)n * D * 2);
  f16*   hB        = (f16*)alloc((size_t)n * D * 2);
  unsigned int* binned = (unsigned int*)hA;  // dead before gemm1 writes hA

  hipMemsetAsync(bcnt, 0, NBMAX * 4, stream);
  hipMemsetAsync(csr + e, 0, 64 * 4, stream);  // pad -> valid index 0

  const int nwg_place = 512;
  k_hist<<<1024, 256, 0, stream>>>(dst, bcnt, e);
  k_bscan<<<1, 1024, 0, stream>>>(bcnt, bbase, bcur);
  k_place<<<nwg_place, 256, 0, stream>>>(src, dst, bcur, binned, e, nwg_place);
  k_csr<<<nb, 256, 0, stream>>>(binned, bbase, csr, deg, isd, row_start, n);

  int gblocks = (n + 63) / 64;
  int ablocks = ((n + 15) / 16) * 4;  // node-groups x 4 slices (grid % 8 == 0)
  // layer 1: MFMA gemm -> slice-major hA; agg -> row-major hB
  k_gemm_m<false><<<gblocks, 256, 0, stream>>>(x, W1, isd, hA, n);
  k_aggs<<<ablocks, 256, 0, stream>>>(hA, csr, row_start, deg, b1, hB, n);
  // layer 2: MFMA gemm (row-major f16 in) -> slice-major hA; agg -> row-major hB
  k_gemm_m<true><<<gblocks, 256, 0, stream>>>(hB, W2, isd, hA, n);
  k_aggs<<<ablocks, 256, 0, stream>>>(hA, csr, row_start, deg, b2, hB, n);
  // classifier
  k_cls<<<(n + 127) / 128, 256, 0, stream>>>(hB, Wl, bl, out, n);
}

// Round 9
// 594.688 us; speedup vs baseline: 1.7195x; 1.0867x over previous
//
#include <hip/hip_runtime.h>
#include <hip/hip_bf16.h>

typedef _Float16 f16;
typedef _Float16 f16x4 __attribute__((ext_vector_type(4)));
typedef _Float16 f16x8 __attribute__((ext_vector_type(8)));
typedef float f32x4 __attribute__((ext_vector_type(4)));

#define D 128
#define N_CLS 40
#define BN 128       // nodes per bucket
#define NBMAX 1024   // padded bucket count

// Gather operand (GEMM output) is feature-sliced: 4 slices x 32 feats = 64B/row,
// slice-major: HS_blk[s][i][f], f in [0,32). Every L1 miss delivers a fully-
// used 64B line; 4 x e = 12.8M lines/dispatch is the compulsory floor for f16
// (H-MSHR model confirmed round 8: 140->123us, FETCH 91->407MB as predicted).
// Aggregation OUTPUT is row-major (consumed densely by GEMM2 / classifier).
// Preprocessing: bucket-major two-stage scatter (random writes confined to
// 16KB L1-resident windows). [round 4: one-pass alternative = 194MB
// write-allocate, 321us]

// ---- 1. bucket histogram of dst (LDS-staged) ----
__global__ __launch_bounds__(256) void k_hist(const int* __restrict__ dst,
                                              int* __restrict__ bcnt, int e) {
  __shared__ int lh[NBMAX];
  for (int j = threadIdx.x; j < NBMAX; j += 256) lh[j] = 0;
  __syncthreads();
  int stride = gridDim.x * blockDim.x;
  for (int q = blockIdx.x * blockDim.x + threadIdx.x; q < e; q += stride)
    atomicAdd(&lh[dst[q] >> 7], 1);
  __syncthreads();
  for (int j = threadIdx.x; j < NBMAX; j += 256)
    if (lh[j]) atomicAdd(&bcnt[j], lh[j]);
}

// ---- 2. exclusive scan of bucket counts ----
__global__ __launch_bounds__(1024) void k_bscan(const int* __restrict__ bcnt,
                                                int* __restrict__ bbase,
                                                int* __restrict__ bcur) {
  __shared__ int sums[NBMAX];
  int t = threadIdx.x;
  int c = bcnt[t];
  sums[t] = c;
  __syncthreads();
  for (int off = 1; off < NBMAX; off <<= 1) {
    int a = (t >= off) ? sums[t - off] : 0;
    __syncthreads();
    sums[t] += a;
    __syncthreads();
  }
  bbase[t] = sums[t] - c;
  bcur[t] = sums[t] - c;
}

// ---- 3. bin edges into bucket-major order ----
__global__ __launch_bounds__(256) void k_place(const int* __restrict__ src,
                                               const int* __restrict__ dst,
                                               int* __restrict__ bcur,
                                               unsigned int* __restrict__ binned,
                                               int e, int nwg) {
  __shared__ int lh[NBMAX];
  __shared__ int lofs[NBMAX];
  __shared__ int lcur[NBMAX];
  int chunk = (e + nwg - 1) / nwg;
  int lo = blockIdx.x * chunk;
  int hi = min(e, lo + chunk);
  int t = threadIdx.x;
  for (int j = t; j < NBMAX; j += 256) { lh[j] = 0; lcur[j] = 0; }
  __syncthreads();
  for (int q = lo + t; q < hi; q += 256) atomicAdd(&lh[dst[q] >> 7], 1);
  __syncthreads();
  for (int j = t; j < NBMAX; j += 256) {
    int c = lh[j];
    lofs[j] = c ? atomicAdd(&bcur[j], c) : 0;
  }
  __syncthreads();
  for (int q = lo + t; q < hi; q += 256) {
    int d = dst[q];
    int b = d >> 7;
    int r = atomicAdd(&lcur[b], 1);
    binned[lofs[b] + r] = ((unsigned int)(d & 127) << 17) | (unsigned int)src[q];
  }
}

// ---- 4. per-bucket counting sort -> CSR + deg + isd + row_start ----
__global__ __launch_bounds__(256) void k_csr(const unsigned int* __restrict__ binned,
                                             const int* __restrict__ bbase,
                                             int* __restrict__ csr,
                                             int* __restrict__ deg,
                                             float* __restrict__ isd,
                                             int* __restrict__ row_start, int n) {
  int b = blockIdx.x;
  int lo = bbase[b], hi = bbase[b + 1];
  __shared__ int h[BN];
  __shared__ int sc[BN];
  __shared__ int cur[BN];
  int t = threadIdx.x;
  if (t < BN) h[t] = 0;
  __syncthreads();
  for (int q = lo + t; q < hi; q += 256) atomicAdd(&h[binned[q] >> 17], 1);
  __syncthreads();
  if (t < BN) sc[t] = h[t];
  __syncthreads();
  for (int off = 1; off < BN; off <<= 1) {
    int a = 0;
    if (t < BN && t >= off) a = sc[t - off];
    __syncthreads();
    if (t < BN) sc[t] += a;
    __syncthreads();
  }
  if (t < BN) {
    int excl = sc[t] - h[t];
    cur[t] = lo + excl;
    int i = b * BN + t;
    if (i < n) {
      deg[i] = h[t];
      isd[i] = rsqrtf((float)(h[t] + 1));
      row_start[i] = lo + excl;
    }
  }
  __syncthreads();
  for (int q = lo + t; q < hi; q += 256) {
    unsigned int u = binned[q];
    int p = atomicAdd(&cur[u >> 17], 1);
    csr[p] = (int)(u & 0x1FFFF);
  }
}

// ---- one-time weight transpose: Wt[c][k] = (f16)W[k*128+c], both layers ----
__global__ __launch_bounds__(256) void k_wt(const float* __restrict__ W1,
                                            const float* __restrict__ W2,
                                            f16* __restrict__ O1,
                                            f16* __restrict__ O2) {
  const float* W = blockIdx.x ? W2 : W1;
  f16* O = blockIdx.x ? O2 : O1;
  __shared__ f16 lt[D][136];
  int t = threadIdx.x;
  for (int q = t; q < D * D; q += 256) {
    int k = q >> 7, c = q & 127;
    lt[c][k] = (f16)W[q];
  }
  __syncthreads();
  for (int q = t; q < D * 16; q += 256) {
    int row = q >> 4, cb = (q & 15) << 3;
    *(f16x8*)(O + ((size_t)row << 7) + cb) = *(const f16x8*)&lt[row][cb];
  }
}

// ---- MFMA GEMM v2: HS_blk = isd[i] * (X @ W), fp32 accum ----
// Block: 256 thr = 4 waves, 64 rows x 128 cols, K=128 in 4 steps of 32.
// A fragment loaded DIRECT from global (no LDS: waves own disjoint rows, no
// reuse; wave covers 16 rows x 64B fully-used lines per k-step).
// B from precomputed Wt (f16 [col][k]) staged via 8 coalesced f16x8 loads.
// C/D (guide-verified m89): col = lane&15, row = (lane>>4)*4 + reg.
// Epilogue: acc -> LDS ot tile -> 4 x fully-coalesced f16x8 stores/thread
// (replaces 32 scalar 2B global stores/thread of v1).
template <bool HALF_IN>
__global__ __launch_bounds__(256) void k_gemm_m(const void* __restrict__ Xv,
                                                const f16* __restrict__ Wtr,
                                                const float* __restrict__ isd,
                                                f16* __restrict__ HS, int n) {
  __shared__ f16 Wt[D][136];
  __shared__ f16 ot[64][136];
  const size_t ss = (size_t)n * 32;  // slice stride in f16 elems (4x32 layout)
  int t = threadIdx.x;
  int r0 = blockIdx.x * 64;
  // stage Wt (32KB) coalesced
  for (int q = t; q < D * 16; q += 256) {
    int row = q >> 4, cb = (q & 15) << 3;
    *(f16x8*)&Wt[row][cb] = *(const f16x8*)(Wtr + ((size_t)row << 7) + cb);
  }
  __syncthreads();

  int wave = t >> 6, lane = t & 63;
  int lw = lane & 15, kg = lane >> 4;
  int arow = r0 + (wave << 4) + lw;
  if (arow >= n) arow = n - 1;  // clamp: tail-block lanes read a valid row
  f32x4 acc[8];
#pragma unroll
  for (int ct = 0; ct < 8; ++ct) acc[ct] = (f32x4)0.f;
#pragma unroll
  for (int ks = 0; ks < 4; ++ks) {
    f16x8 af;
    if (HALF_IN) {
      af = *(const f16x8*)((const f16*)Xv + (size_t)arow * D + ks * 32 + kg * 8);
    } else {
      const float* xp = (const float*)Xv + (size_t)arow * D + ks * 32 + kg * 8;
      float4 x0 = *(const float4*)xp;
      float4 x1 = *(const float4*)(xp + 4);
      af[0] = (f16)x0.x; af[1] = (f16)x0.y; af[2] = (f16)x0.z; af[3] = (f16)x0.w;
      af[4] = (f16)x1.x; af[5] = (f16)x1.y; af[6] = (f16)x1.z; af[7] = (f16)x1.w;
    }
#pragma unroll
    for (int ct = 0; ct < 8; ++ct) {
      f16x8 bf = *(const f16x8*)&Wt[ct * 16 + lw][ks * 32 + kg * 8];
      acc[ct] = __builtin_amdgcn_mfma_f32_16x16x32_f16(af, bf, acc[ct], 0, 0, 0);
    }
  }
  // epilogue: isd scale -> ot tile (scalar LDS writes), then coalesced stores
  int lrow = (wave << 4) + (kg << 2);
  float sv[4];
#pragma unroll
  for (int rr = 0; rr < 4; ++rr) {
    int node = r0 + lrow + rr;
    sv[rr] = isd[node < n ? node : n - 1];
  }
#pragma unroll
  for (int ct = 0; ct < 8; ++ct)
#pragma unroll
    for (int rr = 0; rr < 4; ++rr)
      ot[lrow + rr][ct * 16 + lw] = (f16)(acc[ct][rr] * sv[rr]);
  __syncthreads();
  {
    int orow = t >> 2, cb = (t & 3) << 3;  // node r0+orow, 8 feats at cb
    if (r0 + orow < n) {
#pragma unroll
      for (int s = 0; s < 4; ++s)
        *(f16x8*)(HS + (size_t)s * ss + (size_t)(r0 + orow) * 32 + cb) =
            *(const f16x8*)&ot[orow][s * 32 + cb];
    }
  }
}

__device__ inline f16x8 shfl_xor_f16x8(f16x8 v, int m) {
  union { f16x8 h; int i[4]; } u;
  u.h = v;
#pragma unroll
  for (int k = 0; k < 4; ++k) u.i[k] = __shfl_xor(u.i[k], m);
  return u.h;
}

// ---- sliced aggregation (4 slices x 32 feats, 64B rows) ----
// G[i][s*32..] = relu(isd[i]*(sum HS_blk[s][src] + self) + b)
// block: 256 thr = 4 waves; wave: 4 nodes (16-lane groups); group: 4 edge
// slots (er = r>>2) x 4 row-quarters (q = r&3, 16B each). 16 edges/iter via 4
// loads; each edge row = one fully-used 64B line. csr padded 64 ->
// clamp-free prefetch. slice s = blockIdx&3. Output G is ROW-MAJOR [n][128].
__global__ __launch_bounds__(256) void k_aggs(const f16* __restrict__ HS,
                                              const int* __restrict__ csr,
                                              const int* __restrict__ row_start,
                                              const int* __restrict__ deg,
                                              const float* __restrict__ bias,
                                              f16* __restrict__ G, int n) {
  const size_t ss = (size_t)n * 32;
  int t = threadIdx.x;
  int wave = t >> 6, lane = t & 63;
  int g = lane >> 4, r = lane & 15;
  int s = blockIdx.x & 3;
  int i0 = ((blockIdx.x >> 2) << 4) + (wave << 2) + g;
  bool ok = i0 < n;
  int i = ok ? i0 : n - 1;
  int q = r & 3, er = r >> 2;
  int dg = deg[i];
  const int* cp = csr + row_start[i];           // safe reads: +64 pad
  const char* sbase = (const char*)(HS + (size_t)s * ss);  // wave-uniform
  unsigned qofs = (unsigned)(q << 4);
  f16x8 a0 = (f16x8)0, a1 = (f16x8)0, a2 = (f16x8)0, a3 = (f16x8)0;
  int iA = cp[er];
  int iB = cp[er + 4];
  int iC = cp[er + 8];
  int iD = cp[er + 12];
  for (int u = 0; u < dg; u += 16) {
    unsigned oA = ((unsigned)iA << 6) + qofs;
    unsigned oB = ((unsigned)iB << 6) + qofs;
    unsigned oC = ((unsigned)iC << 6) + qofs;
    unsigned oD = ((unsigned)iD << 6) + qofs;
    iA = cp[u + 16 + er];
    iB = cp[u + 20 + er];
    iC = cp[u + 24 + er];
    iD = cp[u + 28 + er];
    if (u + er < dg)
      a0 += *(const f16x8*)(sbase + oA);
    if (u + 4 + er < dg)
      a1 += *(const f16x8*)(sbase + oB);
    if (u + 8 + er < dg)
      a2 += *(const f16x8*)(sbase + oC);
    if (u + 12 + er < dg)
      a3 += *(const f16x8*)(sbase + oD);
  }
  // reduce the 4 edge slots (lanes with same q differ in bits 2,3)
  f16x8 tv = (a0 + a1) + (a2 + a3);
  tv += shfl_xor_f16x8(tv, 4);
  tv += shfl_xor_f16x8(tv, 8);
  // epilogue: self-loop + isd + bias + relu
  f16x8 svv = *(const f16x8*)(sbase + ((unsigned)i << 6) + qofs);
  float di = rsqrtf((float)(dg + 1));  // == isd[i] (same rsqrt path as k_csr)
  const float* bp = bias + s * 32 + (q << 3);
  float4 b0 = *(const float4*)bp;
  float4 b1 = *(const float4*)(bp + 4);
  float bv[8] = {b0.x, b0.y, b0.z, b0.w, b1.x, b1.y, b1.z, b1.w};
  f16x8 ov;
#pragma unroll
  for (int j = 0; j < 8; ++j) {
    float v = di * ((float)tv[j] + (float)svv[j]) + bv[j];
    v = v > 0.f ? v : 0.f;
    ov[j] = (f16)v;
  }
  if (ok && er == 0)
    *(f16x8*)(G + (size_t)i * D + s * 32 + (q << 3)) = ov;
}

// ---- classifier v3: out = H @ Wl + bl, Wl^T staged in LDS, 128 nodes/block ----
__global__ __launch_bounds__(256) void k_cls(const f16* __restrict__ H,
                                             const float* __restrict__ Wl,
                                             const float* __restrict__ bl,
                                             float* __restrict__ out, int n) {
  __shared__ float wt[N_CLS][D];  // wt[c][k] = Wl[k][c]; rows 512B -> b128 ok
  int t = threadIdx.x;
  for (int q = t; q < D * N_CLS; q += 256) {
    int k = q / N_CLS, c = q - k * N_CLS;  // consecutive q = consecutive Wl
    wt[c][k] = Wl[q];
  }
  int wv = t >> 6, lane = t & 63, g = lane >> 4, l = lane & 15;
  float bb0 = bl[l];
  float bb1 = bl[16 + l];
  float bb2 = (l < 8) ? bl[32 + l] : 0.f;
  __syncthreads();
  int node0 = (blockIdx.x << 7) + (wv << 2) + g;
  for (int it = 0; it < 8; ++it) {
    int node = node0 + it * 16;
    if (node >= n) break;  // no barriers below: divergence safe
    f16x8 h = *(const f16x8*)(H + (size_t)node * D + l * 8);
    float hf[8];
#pragma unroll
    for (int j = 0; j < 8; ++j) hf[j] = (float)h[j];
    float r0 = bb0, r1 = bb1, r2 = bb2;
#pragma unroll 4
    for (int c = 0; c < N_CLS; ++c) {
      const float* wp = &wt[c][l * 8];
      float4 w0 = *(const float4*)wp;
      float4 w1 = *(const float4*)(wp + 4);
      float p = hf[0] * w0.x + hf[1] * w0.y + hf[2] * w0.z + hf[3] * w0.w +
                hf[4] * w1.x + hf[5] * w1.y + hf[6] * w1.z + hf[7] * w1.w;
      p += __shfl_xor(p, 1);
      p += __shfl_xor(p, 2);
      p += __shfl_xor(p, 4);
      p += __shfl_xor(p, 8);
      if ((c & 15) == l) {
        if (c < 16) r0 += p;
        else if (c < 32) r1 += p;
        else r2 += p;
      }
    }
    float* op = out + (size_t)node * N_CLS;
    op[l] = r0;
    op[16 + l] = r1;
    if (l < 8) op[32 + l] = r2;
  }
}

extern "C" void kernel_launch(void* const* d_in, const int* in_sizes, int n_in,
                              void* d_out, int out_size, void* d_ws, size_t ws_size,
                              hipStream_t stream) {
  const float* x  = (const float*)d_in[0];
  const int*   ei = (const int*)d_in[1];
  const float* W1 = (const float*)d_in[2];
  const float* b1 = (const float*)d_in[3];
  const float* W2 = (const float*)d_in[4];
  const float* b2 = (const float*)d_in[5];
  const float* Wl = (const float*)d_in[6];
  const float* bl = (const float*)d_in[7];
  float* out = (float*)d_out;

  const int n = in_sizes[0] / D;  // 100000
  const int e = in_sizes[1] / 2;  // 3200000
  const int* src = ei;
  const int* dst = ei + e;
  const int nb = (n + BN - 1) / BN;  // 782

  char* ws = (char*)d_ws;
  size_t off = 0;
  auto alloc = [&](size_t bytes) -> void* {
    void* p = ws + off;
    off += (bytes + 255) & ~(size_t)255;
    return p;
  };
  int*   bcnt      = (int*)alloc(NBMAX * 4);
  int*   bbase     = (int*)alloc(NBMAX * 4);
  int*   bcur      = (int*)alloc(NBMAX * 4);
  int*   deg       = (int*)alloc((size_t)n * 4);
  int*   row_start = (int*)alloc((size_t)n * 4);
  float* isd       = (float*)alloc((size_t)n * 4);
  int*   csr       = (int*)alloc(((size_t)e + 64) * 4);  // +64 pad: clamp-free
  f16*   Wt1       = (f16*)alloc((size_t)D * D * 2);
  f16*   Wt2       = (f16*)alloc((size_t)D * D * 2);
  f16*   hA        = (f16*)alloc((size_t)n * D * 2);
  f16*   hB        = (f16*)alloc((size_t)n * D * 2);
  unsigned int* binned = (unsigned int*)hA;  // dead before gemm1 writes hA

  hipMemsetAsync(bcnt, 0, NBMAX * 4, stream);
  hipMemsetAsync(csr + e, 0, 64 * 4, stream);  // pad -> valid index 0

  const int nwg_place = 512;
  k_hist<<<1024, 256, 0, stream>>>(dst, bcnt, e);
  k_bscan<<<1, 1024, 0, stream>>>(bcnt, bbase, bcur);
  k_place<<<nwg_place, 256, 0, stream>>>(src, dst, bcur, binned, e, nwg_place);
  k_csr<<<nb, 256, 0, stream>>>(binned, bbase, csr, deg, isd, row_start, n);
  k_wt<<<2, 256, 0, stream>>>(W1, W2, Wt1, Wt2);

  int gblocks = (n + 63) / 64;
  int ablocks = ((n + 15) / 16) * 4;  // node-groups x 4 slices
  // layer 1: MFMA gemm -> slice-major hA; agg -> row-major hB
  k_gemm_m<false><<<gblocks, 256, 0, stream>>>(x, Wt1, isd, hA, n);
  k_aggs<<<ablocks, 256, 0, stream>>>(hA, csr, row_start, deg, b1, hB, n);
  // layer 2: MFMA gemm (row-major f16 in) -> slice-major hA; agg -> row-major hB
  k_gemm_m<true><<<gblocks, 256, 0, stream>>>(hB, Wt2, isd, hA, n);
  k_aggs<<<ablocks, 256, 0, stream>>>(hA, csr, row_start, deg, b2, hB, n);
  // classifier
  k_cls<<<(n + 127) / 128, 256, 0, stream>>>(hB, Wl, bl, out, n);
}